// Round 1
// baseline (266.355 us; speedup 1.0000x reference)
//
#include <hip/hip_runtime.h>
#include <math.h>

#define NCLS   16
#define B_ROWS 65536
#define D_DIM  1024
#define ALPHAc 1.0f
#define BETAc  1.0f
#define GAMMAc 1.0f
#define MARGINc 1.0f

// ws layout (float offsets)
#define OFF_CE    0      // 1 f32 (atomic)
#define OFF_DIST  1      // 16 f32 (atomic)
#define OFF_CNT   32     // 16 int32 (atomic)
#define OFF_CENT  1024   // 16*1024 f32 centroids
#define OFF_PART  32768  // nA * 16384 f32 partial sums

__global__ __launch_bounds__(64) void k_init(float* ws) {
    int t = threadIdx.x;
    if (t < 64) ws[t] = 0.0f;  // covers CE, DIST[16], CNT[16] (bitwise zero)
}

// one thread per row: CE partial + class counts
__global__ __launch_bounds__(256) void k_ce_cnt(const float* __restrict__ logits,
                                                const int* __restrict__ labels,
                                                float* __restrict__ ws) {
    __shared__ int hist[NCLS];
    __shared__ float wsum[4];
    int tid = threadIdx.x;
    if (tid < NCLS) hist[tid] = 0;
    __syncthreads();

    int row = blockIdx.x * 256 + tid;   // grid sized exactly B/256
    const float4* lg = (const float4*)(logits + (size_t)row * 16);
    float4 a = lg[0], b = lg[1], c = lg[2], d = lg[3];
    float m = fmaxf(fmaxf(fmaxf(a.x, a.y), fmaxf(a.z, a.w)),
                    fmaxf(fmaxf(b.x, b.y), fmaxf(b.z, b.w)));
    m = fmaxf(m, fmaxf(fmaxf(c.x, c.y), fmaxf(c.z, c.w)));
    m = fmaxf(m, fmaxf(fmaxf(d.x, d.y), fmaxf(d.z, d.w)));
    float s = expf(a.x - m) + expf(a.y - m) + expf(a.z - m) + expf(a.w - m)
            + expf(b.x - m) + expf(b.y - m) + expf(b.z - m) + expf(b.w - m)
            + expf(c.x - m) + expf(c.y - m) + expf(c.z - m) + expf(c.w - m)
            + expf(d.x - m) + expf(d.y - m) + expf(d.z - m) + expf(d.w - m);
    int lab = labels[row];
    float xl = logits[(size_t)row * 16 + lab];
    float ce = (m + logf(s)) - xl;

    atomicAdd(&hist[lab], 1);

    for (int o = 32; o >= 1; o >>= 1) ce += __shfl_down(ce, o, 64);
    if ((tid & 63) == 0) wsum[tid >> 6] = ce;
    __syncthreads();
    if (tid == 0) {
        float t = wsum[0] + wsum[1] + wsum[2] + wsum[3];
        unsafeAtomicAdd(ws + OFF_CE, t);
    }
    if (tid < NCLS) atomicAdd((int*)ws + OFF_CNT + tid, hist[tid]);
}

// block accumulates 16x1024 class sums in 64KB LDS; thread owns its d-slice -> no atomics
__global__ __launch_bounds__(256) void k_sums(const float* __restrict__ feat,
                                              const int* __restrict__ labels,
                                              float* __restrict__ ws, int rpb) {
    __shared__ float4 sums[NCLS * 256];  // exactly 64 KiB
    int tid = threadIdx.x;
    for (int i = tid; i < NCLS * 256; i += 256) sums[i] = make_float4(0.f, 0.f, 0.f, 0.f);
    __syncthreads();

    int r0 = blockIdx.x * rpb;
    int r1 = r0 + rpb; if (r1 > B_ROWS) r1 = B_ROWS;
    const float4* f4 = (const float4*)feat;

    int r = r0;
    for (; r + 3 < r1; r += 4) {
        int l0 = labels[r], l1 = labels[r + 1], l2 = labels[r + 2], l3 = labels[r + 3];
        float4 v0 = f4[(size_t)r * 256 + tid];
        float4 v1 = f4[(size_t)(r + 1) * 256 + tid];
        float4 v2 = f4[(size_t)(r + 2) * 256 + tid];
        float4 v3 = f4[(size_t)(r + 3) * 256 + tid];
        float4 s0 = sums[l0 * 256 + tid];
        s0.x += v0.x; s0.y += v0.y; s0.z += v0.z; s0.w += v0.w;
        sums[l0 * 256 + tid] = s0;
        float4 s1 = sums[l1 * 256 + tid];
        s1.x += v1.x; s1.y += v1.y; s1.z += v1.z; s1.w += v1.w;
        sums[l1 * 256 + tid] = s1;
        float4 s2 = sums[l2 * 256 + tid];
        s2.x += v2.x; s2.y += v2.y; s2.z += v2.z; s2.w += v2.w;
        sums[l2 * 256 + tid] = s2;
        float4 s3 = sums[l3 * 256 + tid];
        s3.x += v3.x; s3.y += v3.y; s3.z += v3.z; s3.w += v3.w;
        sums[l3 * 256 + tid] = s3;
    }
    for (; r < r1; ++r) {
        int l = labels[r];
        float4 v = f4[(size_t)r * 256 + tid];
        float4 s = sums[l * 256 + tid];
        s.x += v.x; s.y += v.y; s.z += v.z; s.w += v.w;
        sums[l * 256 + tid] = s;
    }
    __syncthreads();
    float4* part = (float4*)(ws + OFF_PART + (size_t)blockIdx.x * 16384);
    for (int i = tid; i < NCLS * 256; i += 256) part[i] = sums[i];
}

// reduce partials -> centroids
__global__ __launch_bounds__(256) void k_cent(float* __restrict__ ws, int nA) {
    int j = blockIdx.x * 256 + threadIdx.x;  // 0..16383, grid 64 blocks
    const float* part = ws + OFF_PART;
    float s = 0.f;
    for (int a = 0; a < nA; ++a) s += part[(size_t)a * 16384 + j];
    int c = j >> 10;
    int cnt = ((const int*)ws)[OFF_CNT + c];
    float safe = cnt > 0 ? (float)cnt : 1.0f;
    ws[OFF_CENT + j] = s / safe;
}

// wave-per-row distance to own-class centroid; centroids stay in L2 (64KB)
__global__ __launch_bounds__(256) void k_dist(const float* __restrict__ feat,
                                              const int* __restrict__ labels,
                                              float* __restrict__ ws, int totalWaves) {
    __shared__ float wdist[4][NCLS];
    int tid = threadIdx.x, w = tid >> 6, lane = tid & 63;
    if (lane < NCLS) wdist[w][lane] = 0.f;
    __syncthreads();
    const float4* f4 = (const float4*)feat;
    const float4* c4 = (const float4*)(ws + OFF_CENT);
    int gw = blockIdx.x * 4 + w;
    for (int r = gw; r < B_ROWS; r += totalWaves) {
        int lab = labels[r];
        float acc = 0.f;
#pragma unroll
        for (int k = 0; k < 4; ++k) {
            float4 v = f4[(size_t)r * 256 + k * 64 + lane];
            float4 c = c4[lab * 256 + k * 64 + lane];
            float dx = v.x - c.x, dy = v.y - c.y, dz = v.z - c.z, dw = v.w - c.w;
            acc += dx * dx + dy * dy + dz * dz + dw * dw;
        }
        for (int o = 32; o >= 1; o >>= 1) acc += __shfl_down(acc, o, 64);
        if (lane == 0) wdist[w][lab] += sqrtf(acc);
    }
    __syncthreads();
    if (tid < NCLS) {
        float s = wdist[0][tid] + wdist[1][tid] + wdist[2][tid] + wdist[3][tid];
        unsafeAtomicAdd(ws + OFF_DIST + tid, s);
    }
}

// single block: inter-class pairs + final combine
__global__ __launch_bounds__(256) void k_final(float* __restrict__ ws, float* __restrict__ out) {
    __shared__ float winter[4];
    __shared__ int wcnt[4];
    int tid = threadIdx.x, w = tid >> 6, lane = tid & 63;
    const float4* c4 = (const float4*)(ws + OFF_CENT);
    const int* cnts = (const int*)ws + OFF_CNT;
    float interAcc = 0.f; int pairAcc = 0;
    for (int p = w; p < 120; p += 4) {
        int i = 0, rem = p;
        while (rem >= 15 - i) { rem -= 15 - i; ++i; }
        int j = i + 1 + rem;
        float acc = 0.f;
#pragma unroll
        for (int k = 0; k < 4; ++k) {
            float4 a = c4[i * 256 + k * 64 + lane];
            float4 b = c4[j * 256 + k * 64 + lane];
            float dx = a.x - b.x, dy = a.y - b.y, dz = a.z - b.z, dw = a.w - b.w;
            acc += dx * dx + dy * dy + dz * dz + dw * dw;
        }
        for (int o = 32; o >= 1; o >>= 1) acc += __shfl_down(acc, o, 64);
        if (lane == 0 && cnts[i] > 0 && cnts[j] > 0) {
            float t = MARGINc - sqrtf(acc);
            if (t > 0.f) interAcc += t;
            pairAcc += 1;
        }
    }
    if (lane == 0) { winter[w] = interAcc; wcnt[w] = pairAcc; }
    __syncthreads();
    if (tid == 0) {
        float interSum = winter[0] + winter[1] + winter[2] + winter[3];
        int np = wcnt[0] + wcnt[1] + wcnt[2] + wcnt[3];
        float inter = np > 0 ? interSum / (float)np : 0.f;
        float intra = 0.f; int nv = 0;
        for (int c = 0; c < NCLS; ++c) {
            int cc = cnts[c];
            if (cc > 0) { intra += ws[OFF_DIST + c] / (float)cc; nv++; }
        }
        intra = nv > 0 ? intra / (float)nv : 0.f;
        float ce = ws[OFF_CE] / (float)B_ROWS;
        out[0] = ALPHAc * ce + BETAc * inter + GAMMAc * intra;
    }
}

extern "C" void kernel_launch(void* const* d_in, const int* in_sizes, int n_in,
                              void* d_out, int out_size, void* d_ws, size_t ws_size,
                              hipStream_t stream) {
    const float* logits = (const float*)d_in[0];
    const int* labels   = (const int*)d_in[1];
    const float* feat   = (const float*)d_in[2];
    float* ws  = (float*)d_ws;
    float* out = (float*)d_out;

    // pick partial-block count from available workspace (512 => 2 blocks/CU)
    size_t wsf = ws_size / 4;
    int nA = 512;
    if (wsf < (size_t)OFF_PART + (size_t)nA * 16384) {
        long avail = (long)wsf - OFF_PART;
        nA = (int)(avail / 16384);
        if (nA < 1) nA = 1;
    }
    int rpb = (B_ROWS + nA - 1) / nA;

    hipLaunchKernelGGL(k_init,   dim3(1),            dim3(64),  0, stream, ws);
    hipLaunchKernelGGL(k_ce_cnt, dim3(B_ROWS / 256), dim3(256), 0, stream, logits, labels, ws);
    hipLaunchKernelGGL(k_sums,   dim3(nA),           dim3(256), 0, stream, feat, labels, ws, rpb);
    hipLaunchKernelGGL(k_cent,   dim3(64),           dim3(256), 0, stream, ws, nA);
    int nC = 2048;
    hipLaunchKernelGGL(k_dist,   dim3(nC),           dim3(256), 0, stream, feat, labels, ws, nC * 4);
    hipLaunchKernelGGL(k_final,  dim3(1),            dim3(256), 0, stream, ws, out);
}